// Round 1
// baseline (222.220 us; speedup 1.0000x reference)
//
#include <hip/hip_runtime.h>
#include <math.h>

#define KNN 16
#define CH 64
#define HID 16
#define NEG_BIG (-3.402823466e+38f)

__device__ __forceinline__ float sigmoidf_(float x) {
    return 1.0f / (1.0f + __expf(-x));
}

// Phase A: channel attention. 16 lanes per point (4 points/wave), lane owns 4 channels (float4).
__global__ __launch_bounds__(256) void kA(const float4* __restrict__ xv,
        const float* __restrict__ W1, const float* __restrict__ b1,
        const float* __restrict__ W2, const float* __restrict__ b2,
        const int* __restrict__ idx,
        float4* __restrict__ outse, float2* __restrict__ rowstat, int n) {
    // w1q[h*16+s] = {W1[(4s+i)*HID + h]}_{i=0..3}  (transposed so lane s, loop h reads float4)
    __shared__ float4 w1q[256];
    __shared__ float4 w2q[256];   // straight float4 copy of W2 (16x64 row-major)
    int t = threadIdx.x;
    {
        int h = t >> 4, s = t & 15;
        float4 a;
        a.x = W1[(4 * s + 0) * HID + h];
        a.y = W1[(4 * s + 1) * HID + h];
        a.z = W1[(4 * s + 2) * HID + h];
        a.w = W1[(4 * s + 3) * HID + h];
        w1q[t] = a;
        w2q[t] = ((const float4*)W2)[t];
    }
    __syncthreads();

    int p = blockIdx.x * 16 + (t >> 4);
    int sub = t & 15;
    if (p >= n) return;

    int jj = idx[p * KNN + sub];          // lane sub preloads idx[p][sub]
    float4 sum = {0.f, 0.f, 0.f, 0.f};
    float4 mx = {NEG_BIG, NEG_BIG, NEG_BIG, NEG_BIG};
    #pragma unroll
    for (int k = 0; k < KNN; ++k) {
        int j = __shfl(jj, k, 16);        // broadcast within 16-lane group
        float4 v = xv[j * 16 + sub];      // one full 256B row per group, coalesced
        sum.x += v.x; sum.y += v.y; sum.z += v.z; sum.w += v.w;
        mx.x = fmaxf(mx.x, v.x); mx.y = fmaxf(mx.y, v.y);
        mx.z = fmaxf(mx.z, v.z); mx.w = fmaxf(mx.w, v.w);
    }
    const float inv_k = 1.0f / KNN;
    float4 mean = {sum.x * inv_k, sum.y * inv_k, sum.z * inv_k, sum.w * inv_k};

    // layer 1 partials: pm[h] = dot4(mean, W1 rows c4..c4+3, col h)
    float pm[HID], px[HID];
    #pragma unroll
    for (int h = 0; h < HID; ++h) {
        float4 w = w1q[h * 16 + sub];
        pm[h] = mean.x * w.x + mean.y * w.y + mean.z * w.z + mean.w * w.w;
        px[h] = mx.x * w.x + mx.y * w.y + mx.z * w.z + mx.w * w.w;
    }
    // fold-reduce across the 16-lane group: lane sub ends holding h == sub
    #pragma unroll
    for (int m = 8; m >= 1; m >>= 1) {
        bool hi = (sub & m) != 0;
        #pragma unroll
        for (int i = 0; i < m; ++i) {
            float sm = hi ? pm[i] : pm[i + m];
            float km = hi ? pm[i + m] : pm[i];
            pm[i] = km + __shfl_xor(sm, m);
            float sx = hi ? px[i] : px[i + m];
            float kx = hi ? px[i + m] : px[i];
            px[i] = kx + __shfl_xor(sx, m);
        }
    }
    float bb = b1[sub];
    float H = fmaxf(pm[0] + bb, 0.0f) + fmaxf(px[0] + bb, 0.0f);

    // layer 2: out4[c] = sum_h H[h] * W2[h][c]
    float4 acc = {0.f, 0.f, 0.f, 0.f};
    #pragma unroll
    for (int h = 0; h < HID; ++h) {
        float Hh = __shfl(H, h, 16);
        float4 w = w2q[h * 16 + sub];
        acc.x += Hh * w.x; acc.y += Hh * w.y; acc.z += Hh * w.z; acc.w += Hh * w.w;
    }
    float4 bq = ((const float4*)b2)[sub];
    float4 own = xv[p * 16 + sub];
    float4 o;
    o.x = own.x * sigmoidf_(acc.x + 2.0f * bq.x);
    o.y = own.y * sigmoidf_(acc.y + 2.0f * bq.y);
    o.z = own.z * sigmoidf_(acc.z + 2.0f * bq.z);
    o.w = own.w * sigmoidf_(acc.w + 2.0f * bq.w);
    outse[p * 16 + sub] = o;

    // per-row stats so phase B gathers 8B/neighbor instead of 256B
    float sm = o.x + o.y + o.z + o.w;
    float sx = fmaxf(fmaxf(o.x, o.y), fmaxf(o.z, o.w));
    #pragma unroll
    for (int m = 8; m >= 1; m >>= 1) {
        sm += __shfl_xor(sm, m);
        sx = fmaxf(sx, __shfl_xor(sx, m));
    }
    if (sub == 0) rowstat[p] = make_float2(sm * (1.0f / 64.0f), sx);
}

// Phase B: z[n] = (mean_k rowmean, max_k rowmax) over knn neighbors
__global__ __launch_bounds__(256) void kB(const int4* __restrict__ idxv,
        const float2* __restrict__ rowstat, float2* __restrict__ z, int n) {
    int i = blockIdx.x * 256 + threadIdx.x;
    if (i >= n) return;
    float zm = 0.0f, zx = NEG_BIG;
    #pragma unroll
    for (int q = 0; q < 4; ++q) {
        int4 jj = idxv[i * 4 + q];
        float2 s0 = rowstat[jj.x];
        float2 s1 = rowstat[jj.y];
        float2 s2 = rowstat[jj.z];
        float2 s3 = rowstat[jj.w];
        zm += s0.x + s1.x + s2.x + s3.x;
        zx = fmaxf(zx, fmaxf(fmaxf(s0.y, s1.y), fmaxf(s2.y, s3.y)));
    }
    z[i] = make_float2(zm * (1.0f / 16.0f), zx);
}

// Phase C1: 27-tap sparse conv over z -> sigmoid gate per point
__global__ __launch_bounds__(256) void kC1(const int* __restrict__ conv_idx,
        const float* __restrict__ conv_w, const float2* __restrict__ z,
        float* __restrict__ sig, int n) {
    __shared__ float cw[54];
    if (threadIdx.x < 54) cw[threadIdx.x] = conv_w[threadIdx.x];
    __syncthreads();
    int i = blockIdx.x * 256 + threadIdx.x;
    if (i >= n) return;
    float acc = 0.0f;
    #pragma unroll
    for (int k = 0; k < 27; ++k) {
        int j = conv_idx[i * 27 + k];
        if (j >= 0) {
            float2 zz = z[j];
            acc += zz.x * cw[2 * k] + zz.y * cw[2 * k + 1];
        }
    }
    sig[i] = sigmoidf_(acc);
}

// Phase C2: out = outse * sig[point], pure streaming
__global__ __launch_bounds__(256) void kC2(const float4* __restrict__ outse,
        const float* __restrict__ sig, float4* __restrict__ out, int n4) {
    int i = blockIdx.x * 256 + threadIdx.x;
    if (i >= n4) return;
    float s = sig[i >> 4];
    float4 v = outse[i];
    out[i] = make_float4(v.x * s, v.y * s, v.z * s, v.w * s);
}

extern "C" void kernel_launch(void* const* d_in, const int* in_sizes, int n_in,
                              void* d_out, int out_size, void* d_ws, size_t ws_size,
                              hipStream_t stream) {
    const float* x_F    = (const float*)d_in[0];
    const float* W1     = (const float*)d_in[1];
    const float* b1     = (const float*)d_in[2];
    const float* W2     = (const float*)d_in[3];
    const float* b2     = (const float*)d_in[4];
    const float* conv_w = (const float*)d_in[5];
    const int*   idx    = (const int*)d_in[6];
    const int*   cidx   = (const int*)d_in[7];
    int n = in_sizes[0] / CH;   // 100000

    char* ws = (char*)d_ws;
    float*  outse   = (float*)ws;                                  // n*64 f32 = 25.6 MB
    float2* rowstat = (float2*)(ws + (size_t)n * CH * 4);          // n float2
    float2* zz      = (float2*)(ws + (size_t)n * CH * 4 + (size_t)n * 8);
    float*  sig     = (float*)(ws + (size_t)n * CH * 4 + (size_t)n * 16);

    int blkA = (n + 15) / 16;
    kA<<<blkA, 256, 0, stream>>>((const float4*)x_F, W1, b1, W2, b2, idx,
                                 (float4*)outse, rowstat, n);
    int blkP = (n + 255) / 256;
    kB<<<blkP, 256, 0, stream>>>((const int4*)idx, rowstat, zz, n);
    kC1<<<blkP, 256, 0, stream>>>(cidx, conv_w, zz, sig, n);
    int n4 = n * (CH / 4);
    int blkE = (n4 + 255) / 256;
    kC2<<<blkE, 256, 0, stream>>>((const float4*)outse, sig, (float4*)d_out, n4);
}

// Round 2
// 200.402 us; speedup vs baseline: 1.1089x; 1.1089x over previous
//
#include <hip/hip_runtime.h>
#include <math.h>

#define KNN 16
#define CH 64
#define HID 16
#define NEG_BIG (-3.402823466e+38f)

__device__ __forceinline__ float sigmoidf_(float x) {
    return 1.0f / (1.0f + __expf(-x));
}

// fold-reduce across a 16-lane group: on entry v[h] = this lane's partial for
// output h; on exit, return value on lane `sub` is the full sum for h == sub.
__device__ __forceinline__ float fold16(float v[HID], int sub) {
    #pragma unroll
    for (int m = 8; m >= 1; m >>= 1) {
        bool hi = (sub & m) != 0;
        #pragma unroll
        for (int i = 0; i < m; ++i) {
            float s    = hi ? v[i] : v[i + m];
            float keep = hi ? v[i + m] : v[i];
            v[i] = keep + __shfl_xor(s, m);
        }
    }
    return v[0];
}

// Phase A: channel attention. 16 lanes per point (4 points/wave), lane owns 4
// channels (float4). __launch_bounds__(256,4): allow up to 128 VGPRs so the 16
// staged gather loads + MLP arrays live in registers (32-VGPR alloc in R1 was
// the bottleneck: no memory-level parallelism on the random gathers).
__global__ __launch_bounds__(256, 4) void kA(const float4* __restrict__ xv,
        const float* __restrict__ W1, const float* __restrict__ b1,
        const float* __restrict__ W2, const float* __restrict__ b2,
        const int* __restrict__ idx,
        float4* __restrict__ outse, float2* __restrict__ rowstat, int n) {
    // w1q[h*16+s] = {W1[(4s+i)*HID + h]}_{i=0..3}
    __shared__ float4 w1q[256];
    __shared__ float4 w2q[256];   // straight float4 copy of W2 (16x64 row-major)
    int t = threadIdx.x;
    {
        int h = t >> 4, s = t & 15;
        float4 a;
        a.x = W1[(4 * s + 0) * HID + h];
        a.y = W1[(4 * s + 1) * HID + h];
        a.z = W1[(4 * s + 2) * HID + h];
        a.w = W1[(4 * s + 3) * HID + h];
        w1q[t] = a;
        w2q[t] = ((const float4*)W2)[t];
    }
    __syncthreads();

    int p = blockIdx.x * 16 + (t >> 4);
    int sub = t & 15;
    if (p >= n) return;

    // hoist all 16 neighbor indices, then issue all 16 gathers back-to-back so
    // they are simultaneously in flight (each inst = 1 KB/wave, coalesced).
    int jj = idx[p * KNN + sub];
    int jall[KNN];
    #pragma unroll
    for (int k = 0; k < KNN; ++k) jall[k] = __shfl(jj, k, 16);

    float4 vbuf[KNN];
    #pragma unroll
    for (int k = 0; k < KNN; ++k) vbuf[k] = xv[jall[k] * 16 + sub];
    float4 own = xv[p * 16 + sub];        // also in flight with the gathers
    float bb = b1[sub];
    float4 bq = ((const float4*)b2)[sub];

    float4 sum = vbuf[0];
    float4 mx  = vbuf[0];
    #pragma unroll
    for (int k = 1; k < KNN; ++k) {
        float4 v = vbuf[k];
        sum.x += v.x; sum.y += v.y; sum.z += v.z; sum.w += v.w;
        mx.x = fmaxf(mx.x, v.x); mx.y = fmaxf(mx.y, v.y);
        mx.z = fmaxf(mx.z, v.z); mx.w = fmaxf(mx.w, v.w);
    }
    const float inv_k = 1.0f / KNN;
    float4 mean = {sum.x * inv_k, sum.y * inv_k, sum.z * inv_k, sum.w * inv_k};

    // layer 1, mean path then max path (halves peak live-array pressure)
    float Hm, Hx;
    {
        float pm[HID];
        #pragma unroll
        for (int h = 0; h < HID; ++h) {
            float4 w = w1q[h * 16 + sub];
            pm[h] = mean.x * w.x + mean.y * w.y + mean.z * w.z + mean.w * w.w;
        }
        Hm = fold16(pm, sub);
    }
    {
        float px[HID];
        #pragma unroll
        for (int h = 0; h < HID; ++h) {
            float4 w = w1q[h * 16 + sub];
            px[h] = mx.x * w.x + mx.y * w.y + mx.z * w.z + mx.w * w.w;
        }
        Hx = fold16(px, sub);
    }
    float H = fmaxf(Hm + bb, 0.0f) + fmaxf(Hx + bb, 0.0f);

    // layer 2: out4[c] = sum_h H[h] * W2[h][c]
    float4 acc = {0.f, 0.f, 0.f, 0.f};
    #pragma unroll
    for (int h = 0; h < HID; ++h) {
        float Hh = __shfl(H, h, 16);
        float4 w = w2q[h * 16 + sub];
        acc.x += Hh * w.x; acc.y += Hh * w.y; acc.z += Hh * w.z; acc.w += Hh * w.w;
    }
    float4 o;
    o.x = own.x * sigmoidf_(acc.x + 2.0f * bq.x);
    o.y = own.y * sigmoidf_(acc.y + 2.0f * bq.y);
    o.z = own.z * sigmoidf_(acc.z + 2.0f * bq.z);
    o.w = own.w * sigmoidf_(acc.w + 2.0f * bq.w);
    outse[p * 16 + sub] = o;

    // per-row stats so phase B gathers 8B/neighbor instead of 256B
    float sm = o.x + o.y + o.z + o.w;
    float sx = fmaxf(fmaxf(o.x, o.y), fmaxf(o.z, o.w));
    #pragma unroll
    for (int m = 8; m >= 1; m >>= 1) {
        sm += __shfl_xor(sm, m);
        sx = fmaxf(sx, __shfl_xor(sx, m));
    }
    if (sub == 0) rowstat[p] = make_float2(sm * (1.0f / 64.0f), sx);
}

// Phase B: z[n] = (mean_k rowmean, max_k rowmax) over knn neighbors
__global__ __launch_bounds__(256) void kB(const int4* __restrict__ idxv,
        const float2* __restrict__ rowstat, float2* __restrict__ z, int n) {
    int i = blockIdx.x * 256 + threadIdx.x;
    if (i >= n) return;
    float zm = 0.0f, zx = NEG_BIG;
    #pragma unroll
    for (int q = 0; q < 4; ++q) {
        int4 jj = idxv[i * 4 + q];
        float2 s0 = rowstat[jj.x];
        float2 s1 = rowstat[jj.y];
        float2 s2 = rowstat[jj.z];
        float2 s3 = rowstat[jj.w];
        zm += s0.x + s1.x + s2.x + s3.x;
        zx = fmaxf(zx, fmaxf(fmaxf(s0.y, s1.y), fmaxf(s2.y, s3.y)));
    }
    z[i] = make_float2(zm * (1.0f / 16.0f), zx);
}

// Phase C1: 27-tap sparse conv over z -> sigmoid gate per point
__global__ __launch_bounds__(256) void kC1(const int* __restrict__ conv_idx,
        const float* __restrict__ conv_w, const float2* __restrict__ z,
        float* __restrict__ sig, int n) {
    __shared__ float cw[54];
    if (threadIdx.x < 54) cw[threadIdx.x] = conv_w[threadIdx.x];
    __syncthreads();
    int i = blockIdx.x * 256 + threadIdx.x;
    if (i >= n) return;
    float acc = 0.0f;
    #pragma unroll
    for (int k = 0; k < 27; ++k) {
        int j = conv_idx[i * 27 + k];
        if (j >= 0) {
            float2 zz = z[j];
            acc += zz.x * cw[2 * k] + zz.y * cw[2 * k + 1];
        }
    }
    sig[i] = sigmoidf_(acc);
}

// Phase C2: out = outse * sig[point], pure streaming
__global__ __launch_bounds__(256) void kC2(const float4* __restrict__ outse,
        const float* __restrict__ sig, float4* __restrict__ out, int n4) {
    int i = blockIdx.x * 256 + threadIdx.x;
    if (i >= n4) return;
    float s = sig[i >> 4];
    float4 v = outse[i];
    out[i] = make_float4(v.x * s, v.y * s, v.z * s, v.w * s);
}

extern "C" void kernel_launch(void* const* d_in, const int* in_sizes, int n_in,
                              void* d_out, int out_size, void* d_ws, size_t ws_size,
                              hipStream_t stream) {
    const float* x_F    = (const float*)d_in[0];
    const float* W1     = (const float*)d_in[1];
    const float* b1     = (const float*)d_in[2];
    const float* W2     = (const float*)d_in[3];
    const float* b2     = (const float*)d_in[4];
    const float* conv_w = (const float*)d_in[5];
    const int*   idx    = (const int*)d_in[6];
    const int*   cidx   = (const int*)d_in[7];
    int n = in_sizes[0] / CH;   // 100000

    char* ws = (char*)d_ws;
    float*  outse   = (float*)ws;                                  // n*64 f32 = 25.6 MB
    float2* rowstat = (float2*)(ws + (size_t)n * CH * 4);          // n float2
    float2* zz      = (float2*)(ws + (size_t)n * CH * 4 + (size_t)n * 8);
    float*  sig     = (float*)(ws + (size_t)n * CH * 4 + (size_t)n * 16);

    int blkA = (n + 15) / 16;
    kA<<<blkA, 256, 0, stream>>>((const float4*)x_F, W1, b1, W2, b2, idx,
                                 (float4*)outse, rowstat, n);
    int blkP = (n + 255) / 256;
    kB<<<blkP, 256, 0, stream>>>((const int4*)idx, rowstat, zz, n);
    kC1<<<blkP, 256, 0, stream>>>(cidx, conv_w, zz, sig, n);
    int n4 = n * (CH / 4);
    int blkE = (n4 + 255) / 256;
    kC2<<<blkE, 256, 0, stream>>>((const float4*)outse, sig, (float4*)d_out, n4);
}